// Round 7
// baseline (612.950 us; speedup 1.0000x reference)
//
#include <hip/hip_runtime.h>
#include <hip/hip_bf16.h>
#include <cstdint>

#define N_ATOMS 100000
#define NFEAT   256
#define NMOL    1024
#define NU      6256    // 100096 / 16 atoms per unit
#define NPAD    100096  // NU*16: Ab and H1 padded to this many rows

static constexpr float SCALE_C = 5.992277830325989f;
static constexpr float SHIFT_C = -406274.63784969115f;

typedef __attribute__((ext_vector_type(8))) short short8;    // bf16x8 MFMA operand
typedef __attribute__((ext_vector_type(4))) float float4_t;  // f32x4 accumulator

__device__ __forceinline__ unsigned short f2bf(float x) {
    union { float f; uint32_t u; } v; v.f = x;
    uint32_t r = (v.u + 0x7fffu + ((v.u >> 16) & 1u)) >> 16;
    return (unsigned short)r;
}

// pack two fp32 -> two bf16 (+0x8000 truncate-high, bit-identical to the
// conversion used in every passing round) in one v_perm
__device__ __forceinline__ uint32_t pk(float lo, float hi) {
    union { float f; uint32_t u; } a, b; a.f = lo; b.f = hi;
    return __builtin_amdgcn_perm(b.u + 0x8000u, a.u + 0x8000u, 0x07060302u);
}

__device__ __forceinline__ float silu(float x) {
    return x / (1.0f + __expf(-x));
}

// async global->LDS, 16B/lane; LDS dest wave-uniform, lane i lands at +i*16B
__device__ __forceinline__ void async16(void* lds, const void* g) {
    __builtin_amdgcn_global_load_lds(
        (const __attribute__((address_space(1))) unsigned int*)(uintptr_t)g,
        (__attribute__((address_space(3))) unsigned int*)(uint32_t)(uintptr_t)lds,
        16, 0, 0);
}

// Full 256x256 W image in LDS (R4-verified layout, 0 bank conflicts):
//   pos = (kc>>4)*32768 + n*128 + (((kc&15) ^ (n&15))<<3)  [+ (k&7)]
__device__ __forceinline__ short8 wfrag(const unsigned short* Wlds, int n, int kc) {
    return *(const short8*)&Wlds[((kc >> 4) << 15) + n * 128 +
                                 ((((kc & 15) ^ (n & 15)) & 15) << 3)];
}

// ---------------------------------------------------------------------------
// Prep: b<512: W1,W2 fp32 -> bf16 swizzled images + out[]=SHIFT.
// 512<=b<6762: A fp32 -> Ab bf16 (pk rounding). 6762<=b<6768: zero-fill
// Ab pad rows 100000..100095 so the gemms are fully branchless.
// ---------------------------------------------------------------------------
__global__ void prep(const float* __restrict__ W1, const float* __restrict__ W2,
                     const float* __restrict__ A,
                     unsigned short* __restrict__ W1i, unsigned short* __restrict__ W2i,
                     unsigned short* __restrict__ Ab, float* __restrict__ out) {
    const int b = blockIdx.x, tid = threadIdx.x;
    if (b < 512) {
        int g = b * 256 + tid;                       // 0 .. 131071
        const float* W = (g < 65536) ? W1 : W2;
        unsigned short* Wi = (g < 65536) ? W1i : W2i;
        int idx = g & 65535;
        int k = idx >> 8, n = idx & 255;
        int kc = (k >> 3) & 15;
        int pos = ((k >> 7) << 15) + n * 128 + (((kc ^ (n & 15)) & 15) << 3) + (k & 7);
        Wi[pos] = f2bf(W[idx]);
        if (g < NMOL) out[g] = SHIFT_C;
    } else if (b < 6762) {
        // 6250 blocks x 256 thr x 16 floats = 25,600,000 = N_ATOMS*256 exactly
        int t = (b - 512) * 256 + tid;
        const float4* af = (const float4*)(A + (size_t)t * 16);
        float4 x0 = af[0], x1 = af[1], x2 = af[2], x3 = af[3];
        uint4 o0 = make_uint4(pk(x0.x, x0.y), pk(x0.z, x0.w),
                              pk(x1.x, x1.y), pk(x1.z, x1.w));
        uint4 o1 = make_uint4(pk(x2.x, x2.y), pk(x2.z, x2.w),
                              pk(x3.x, x3.y), pk(x3.z, x3.w));
        ((uint4*)Ab)[(size_t)t * 2]     = o0;
        ((uint4*)Ab)[(size_t)t * 2 + 1] = o1;
    } else {
        // zero pad rows: 6 blocks x 256 thr x 16 shorts = 24576 = 96*256
        int idx = (b - 6762) * 256 + tid;
        uint4 z = make_uint4(0, 0, 0, 0);
        ((uint4*)(Ab + (size_t)N_ATOMS * 256))[idx * 2]     = z;
        ((uint4*)(Ab + (size_t)N_ATOMS * 256))[idx * 2 + 1] = z;
    }
}

// ---------------------------------------------------------------------------
// Layer 1: H1 = silu(Ab @ W1 + b1), Ab pre-converted bf16 (NPAD rows).
// R14 synthesis: R0(8w) == R3(16w) == 61us -> wave count is not the lever;
// the per-k-step dependent-load stall is. Fixing it needs registers, and
// registers need 8 waves: at 2 waves/SIMD the budget is 256/wave (R0 ran
// 152 with no spill); every 16-wave variant (128/wave) spilled (R4-R6,
// ~500 MB scratch each). So: R0 structure (full 256-col units, full 128 KB
// W in LDS, ONE barrier, 1 block/CU, 8 waves) + whole-unit-upfront a[8]
// (bf16, 32 regs; 8 independent 16B loads = ONE latency exposure/unit) +
// steal-ahead overlap + zero pack-VALU in the k-loop. ~184 regs < 256.
// ---------------------------------------------------------------------------
__global__ __launch_bounds__(512, 2)
void gemm1(const unsigned short* __restrict__ Ab, const unsigned short* __restrict__ Wimg,
           const float* __restrict__ b1, unsigned short* __restrict__ H1) {
    __shared__ unsigned short Wlds[65536];   // 128 KB: full W image
    __shared__ float b1L[256];
    __shared__ int uctr;

    const int tid = threadIdx.x;
    const int w = tid >> 6, lane = tid & 63;
    const int fl = lane & 15, qd = lane >> 4;
    const int bslot = blockIdx.x;            // 256 blocks

#pragma unroll
    for (int i = 0; i < 16; ++i)
        async16(&Wlds[(w * 16 + i) * 512], Wimg + (w * 16 + i) * 512 + lane * 8);
    if (tid < 64) ((float4*)b1L)[tid] = ((const float4*)b1)[tid];
    if (tid == 0) uctr = 0;
    __syncthreads();

    int t;
    { int tt = 0; if (lane == 0) tt = atomicAdd(&uctr, 1); t = __shfl(tt, 0); }

    for (;;) {
        const int u = bslot + (t << 8);       // stride-256 across slots
        if (u >= NU) break;

        const int row = u * 16 + fl;          // this lane's atom (pad rows real)
        const unsigned short* ap = Ab + (size_t)row * 256 + qd * 8;

        // whole unit upfront: 8 independent 16B bf16 loads (32 VGPRs)
        short8 a[8];
#pragma unroll
        for (int s = 0; s < 8; ++s) a[s] = *(const short8*)(ap + s * 32);

        // steal next unit while loads are in flight
        { int tt = 0; if (lane == 0) tt = atomicAdd(&uctr, 1); t = __shfl(tt, 0); }

        float4_t acc[16] = {};
#pragma unroll
        for (int s = 0; s < 8; ++s) {
            const int kc = s * 4 + qd;
#pragma unroll
            for (int j = 0; j < 16; ++j) {
                short8 wf = wfrag(Wlds, j * 16 + fl, kc);
                acc[j] = __builtin_amdgcn_mfma_f32_16x16x32_bf16(wf, a[s], acc[j], 0, 0, 0);
            }
        }

        // branchless store: pad rows are real memory
#pragma unroll
        for (int j = 0; j < 16; ++j) {
            int nb = j * 16 + qd * 4;
            float4 b4 = *(const float4*)&b1L[nb];
            uint2 o;
            o.x = pk(silu(acc[j][0] + b4.x), silu(acc[j][1] + b4.y));
            o.y = pk(silu(acc[j][2] + b4.z), silu(acc[j][3] + b4.w));
            *(uint2*)&H1[(size_t)row * 256 + nb] = o;
        }
    }
}

// ---------------------------------------------------------------------------
// Layer 2+3+pool: out[mol] += SCALE*(silu(H1@W2+b2).W3 + b3). R0 structure
// (full 256-col units) + R14 upfront h[8] + steal-ahead; b2/W3 staged in
// LDS (saves 32 arch regs vs R0's bbv/w3v arrays). acc[16]=64 + h[8]=32 +
// ~60 arch ~= 156 < 256. Pooling via LDS bucket[1024], one global atomic
// per nonzero bucket at the end; b3 added once per atom.
// ---------------------------------------------------------------------------
__global__ __launch_bounds__(512, 2)
void gemm2(const unsigned short* __restrict__ H1, const unsigned short* __restrict__ Wimg,
           const float* __restrict__ b2, const float* __restrict__ W3,
           const float* __restrict__ b3, const int* __restrict__ batch,
           float* __restrict__ out) {
    __shared__ unsigned short Wlds[65536];   // 128 KB
    __shared__ float bucket[NMOL];           // 4 KB
    __shared__ float bL2[256], w3L[256];     // 2 KB
    __shared__ int uctr;

    const int tid = threadIdx.x;
    const int w = tid >> 6, lane = tid & 63;
    const int fl = lane & 15, qd = lane >> 4;
    const int bslot = blockIdx.x;

#pragma unroll
    for (int i = 0; i < 16; ++i)
        async16(&Wlds[(w * 16 + i) * 512], Wimg + (w * 16 + i) * 512 + lane * 8);
    bucket[tid] = 0.0f;
    bucket[tid + 512] = 0.0f;
    if (tid < 256) {
        bL2[tid] = b2[tid];
        w3L[tid] = W3[tid];
    }
    if (tid == 0) uctr = 0;
    __syncthreads();

    const float b3v = b3[0];

    int t;
    { int tt = 0; if (lane == 0) tt = atomicAdd(&uctr, 1); t = __shfl(tt, 0); }

    for (;;) {
        const int u = bslot + (t << 8);
        if (u >= NU) break;

        const int ubase = u * 16;
        const int row = ubase + fl;
        const unsigned short* hp = H1 + (size_t)row * 256 + qd * 8;

        // whole unit upfront: 8 independent 16B loads (32 VGPRs)
        short8 h[8];
#pragma unroll
        for (int s = 0; s < 8; ++s) h[s] = *(const short8*)(hp + s * 32);

        { int tt = 0; if (lane == 0) tt = atomicAdd(&uctr, 1); t = __shfl(tt, 0); }

        float4_t acc[16] = {};
#pragma unroll
        for (int s = 0; s < 8; ++s) {
            const int kc = s * 4 + qd;
#pragma unroll
            for (int nt = 0; nt < 16; ++nt) {
                short8 wf = wfrag(Wlds, nt * 16 + fl, kc);
                acc[nt] = __builtin_amdgcn_mfma_f32_16x16x32_bf16(h[s], wf, acc[nt], 0, 0, 0);
            }
        }

        // acc[nt][r]: atom = ubase + qd*4 + r, col = nt*16 + fl
        float rs[4] = {};
#pragma unroll
        for (int nt = 0; nt < 16; ++nt) {
            float bb = bL2[nt * 16 + fl];
            float w3 = w3L[nt * 16 + fl];
#pragma unroll
            for (int r = 0; r < 4; ++r)
                rs[r] += silu(acc[nt][r] + bb) * w3;
        }
#pragma unroll
        for (int r = 0; r < 4; ++r) {
            float v = rs[r];
            v += __shfl_xor(v, 1);
            v += __shfl_xor(v, 2);
            v += __shfl_xor(v, 4);
            v += __shfl_xor(v, 8);
            rs[r] = v;
        }
        if (fl == 0) {
            int atom0 = ubase + qd * 4;
            if (atom0 < N_ATOMS) {   // excludes pad atoms; %4==0 -> 4 rows valid
                int4 mb = *(const int4*)&batch[atom0];
                float v0 = rs[0] + b3v, v1 = rs[1] + b3v,
                      v2 = rs[2] + b3v, v3 = rs[3] + b3v;
                if (mb.x == mb.w) {
                    atomicAdd(&bucket[mb.x], (v0 + v1) + (v2 + v3));
                } else {
                    atomicAdd(&bucket[mb.x], v0);
                    atomicAdd(&bucket[mb.y], v1);
                    atomicAdd(&bucket[mb.z], v2);
                    atomicAdd(&bucket[mb.w], v3);
                }
            }
        }
    }
    __syncthreads();
#pragma unroll
    for (int i = 0; i < 2; ++i) {
        int m = tid + i * 512;
        float v = bucket[m];
        if (v != 0.0f) atomicAdd(&out[m], v * SCALE_C);
    }
}

// ---------------------------------------------------------------------------
extern "C" void kernel_launch(void* const* d_in, const int* in_sizes, int n_in,
                              void* d_out, int out_size, void* d_ws, size_t ws_size,
                              hipStream_t stream) {
    const float* A     = (const float*)d_in[0];
    const int*   batch = (const int*)d_in[1];
    const float* W1    = (const float*)d_in[2];
    const float* b1    = (const float*)d_in[3];
    const float* W2    = (const float*)d_in[4];
    const float* b2    = (const float*)d_in[5];
    const float* W3    = (const float*)d_in[6];
    const float* b3    = (const float*)d_in[7];
    float* out = (float*)d_out;

    unsigned short* H1  = (unsigned short*)d_ws;            // NPAD*256 bf16
    unsigned short* W1i = H1 + (size_t)NPAD * NFEAT;        // 65536 shorts
    unsigned short* W2i = W1i + 65536;                      // 65536 shorts
    unsigned short* Ab  = W2i + 65536;                      // NPAD*256 bf16

    prep<<<dim3(6768), 256, 0, stream>>>(W1, W2, A, W1i, W2i, Ab, out);
    gemm1<<<dim3(256), 512, 0, stream>>>(Ab, W1i, b1, H1);
    gemm2<<<dim3(256), 512, 0, stream>>>(H1, W2i, b2, W3, b3, batch, out);
}

// Round 8
// 234.777 us; speedup vs baseline: 2.6108x; 2.6108x over previous
//
#include <hip/hip_runtime.h>
#include <hip/hip_bf16.h>
#include <cstdint>

#define N_ATOMS 100000
#define NFEAT   256
#define NMOL    1024
#define NT      6250    // 100000 / 16 atoms per tile (exact)

static constexpr float SCALE_C = 5.992277830325989f;
static constexpr float SHIFT_C = -406274.63784969115f;

typedef __attribute__((ext_vector_type(8))) short short8;    // bf16x8 MFMA operand
typedef __attribute__((ext_vector_type(4))) float float4_t;  // f32x4 accumulator

__device__ __forceinline__ unsigned short f2bf(float x) {
    union { float f; uint32_t u; } v; v.f = x;
    uint32_t r = (v.u + 0x7fffu + ((v.u >> 16) & 1u)) >> 16;
    return (unsigned short)r;
}

// pack two fp32 -> two bf16 in one v_perm (same rounding as all passing rounds)
__device__ __forceinline__ uint32_t pk(float lo, float hi) {
    union { float f; uint32_t u; } a, b; a.f = lo; b.f = hi;
    return __builtin_amdgcn_perm(b.u + 0x8000u, a.u + 0x8000u, 0x07060302u);
}

__device__ __forceinline__ float silu(float x) {
    return x / (1.0f + __expf(-x));
}

// async global->LDS, 16B/lane; LDS dest wave-uniform, lane i lands at +i*16B
__device__ __forceinline__ void async16(void* lds, const void* g) {
    __builtin_amdgcn_global_load_lds(
        (const __attribute__((address_space(1))) unsigned int*)(uintptr_t)g,
        (__attribute__((address_space(3))) unsigned int*)(uint32_t)(uintptr_t)lds,
        16, 0, 0);
}

// Full 256x256 W image in LDS (R4-verified layout, 0 bank conflicts):
//   pos = (kc>>4)*32768 + n*128 + (((kc&15) ^ (n&15))<<3)  [+ (k&7)]
__device__ __forceinline__ short8 wfrag(const unsigned short* Wlds, int n, int kc) {
    return *(const short8*)&Wlds[((kc >> 4) << 15) + n * 128 +
                                 ((((kc & 15) ^ (n & 15)) & 15) << 3)];
}

// k-major tile image for A/H1 (R15): element (row,k) of tile T=row>>4 at
// short-pos T*4096 + (k>>3)*128 + (row&15)*8 + (k&7).
//  - staging: tile = contiguous 8 KB, linear async16, perfectly coalesced
//  - ds_read: lane(fl,qd) step s reads 16B at (qd+s*4)*256B + fl*16B:
//    each qd-group = 256 consecutive bytes -> exact bank floor, 0 conflicts

// ---------------------------------------------------------------------------
// Prep: b<NT: A fp32 tile -> k-major bf16 image (one 16x256 tile per block).
//       b>=NT: W1,W2 fp32 -> bf16 swizzled W images + out[]=SHIFT.
// ---------------------------------------------------------------------------
__global__ void prep(const float* __restrict__ W1, const float* __restrict__ W2,
                     const float* __restrict__ A,
                     unsigned short* __restrict__ W1i, unsigned short* __restrict__ W2i,
                     unsigned short* __restrict__ Aimg, float* __restrict__ out) {
    const int b = blockIdx.x, tid = threadIdx.x;
    if (b < NT) {
        const int r = tid >> 4, k0 = tid & 15;       // row 0..15, 16-elem k-group
        const float4* src = (const float4*)(A + ((size_t)b * 16 + r) * 256 + k0 * 16);
        float4 x0 = src[0], x1 = src[1], x2 = src[2], x3 = src[3];
        uint4 o0 = make_uint4(pk(x0.x, x0.y), pk(x0.z, x0.w),
                              pk(x1.x, x1.y), pk(x1.z, x1.w));
        uint4 o1 = make_uint4(pk(x2.x, x2.y), pk(x2.z, x2.w),
                              pk(x3.x, x3.y), pk(x3.z, x3.w));
        unsigned short* dst = Aimg + (size_t)b * 4096 + (k0 * 2) * 128 + r * 8;
        *(uint4*)dst         = o0;                   // k-chunk k0*2
        *(uint4*)(dst + 128) = o1;                   // k-chunk k0*2+1
    } else {
        int g = (b - NT) * 256 + tid;                // 0 .. 131071
        const float* W = (g < 65536) ? W1 : W2;
        unsigned short* Wi = (g < 65536) ? W1i : W2i;
        int idx = g & 65535;
        int k = idx >> 8, n = idx & 255;
        int kc = (k >> 3) & 15;
        int pos = ((k >> 7) << 15) + n * 128 + (((kc ^ (n & 15)) & 15) << 3) + (k & 7);
        Wi[pos] = f2bf(W[idx]);
        if (g < NMOL) out[g] = SHIFT_C;
    }
}

// ---------------------------------------------------------------------------
// Layer 1: H1 = silu(A @ W1 + b1). R15 structure: block-cooperative tiles of
// 16 atoms; full W (128 KB) + double-buffered 8 KB A-tile in LDS staged by
// global_load_lds (ZERO VGPR cost -- R12-R14's register prefetch spilled
// ~500 MB/round; this takes prefetch out of the register file entirely).
// 8 waves = 8 col-32 quarters, acc[2] = 8 AGPRs. One barrier per tile;
// stage issued at loop top hides under ~700cy compute; H1 stores DEFERRED
// past the barrier so its vmcnt(0) drain never waits on fresh stores.
// Static tiles t = blockIdx + i*256 (4% tail imbalance). Branchless: NT
// divides N_ATOMS exactly.
// ---------------------------------------------------------------------------
__global__ __launch_bounds__(512)
void gemm1(const unsigned short* __restrict__ Aimg, const unsigned short* __restrict__ Wimg,
           const float* __restrict__ b1, unsigned short* __restrict__ H1img) {
    __shared__ unsigned short Wlds[65536];     // 128 KB
    __shared__ unsigned short Albuf[2][4096];  // 2 x 8 KB

    const int tid = threadIdx.x;
    const int w = tid >> 6, lane = tid & 63;
    const int fl = lane & 15, qd = lane >> 4;
    const int q = w;                           // col-quarter (32 cols)

#pragma unroll
    for (int i = 0; i < 16; ++i)
        async16(&Wlds[(w * 16 + i) * 512], Wimg + (w * 16 + i) * 512 + lane * 8);

    const float4 bb0 = *(const float4*)&b1[q * 32 + qd * 4];
    const float4 bb1 = *(const float4*)&b1[q * 32 + 16 + qd * 4];

    int t = blockIdx.x;
    async16(&Albuf[0][w * 512], Aimg + (size_t)t * 4096 + w * 512 + lane * 8);
    asm volatile("s_waitcnt vmcnt(0)" ::: "memory");
    __syncthreads();

    int cur = 0, tp = -1;
    float4_t aP0, aP1;
    while (t < NT) {
        const int tn = t + 256;
        if (tn < NT)
            async16(&Albuf[cur ^ 1][w * 512], Aimg + (size_t)tn * 4096 + w * 512 + lane * 8);

        // deferred store of PREVIOUS tile (issued just after barrier ->
        // retired long before the next barrier's drain)
        if (tp >= 0) {
            uint2 o;
            o.x = pk(silu(aP0[0] + bb0.x), silu(aP0[1] + bb0.y));
            o.y = pk(silu(aP0[2] + bb0.z), silu(aP0[3] + bb0.w));
            *(uint2*)&H1img[(size_t)tp * 4096 + (q * 4 + (qd >> 1)) * 128 + fl * 8 + (qd & 1) * 4] = o;
            o.x = pk(silu(aP1[0] + bb1.x), silu(aP1[1] + bb1.y));
            o.y = pk(silu(aP1[2] + bb1.z), silu(aP1[3] + bb1.w));
            *(uint2*)&H1img[(size_t)tp * 4096 + (q * 4 + 2 + (qd >> 1)) * 128 + fl * 8 + (qd & 1) * 4] = o;
        }

        float4_t a0 = {}, a1 = {};
#pragma unroll
        for (int s = 0; s < 8; ++s) {
            short8 av = *(const short8*)&Albuf[cur][(qd + s * 4) * 128 + fl * 8];
            short8 wf0 = wfrag(Wlds, q * 32 + fl, s * 4 + qd);
            short8 wf1 = wfrag(Wlds, q * 32 + 16 + fl, s * 4 + qd);
            a0 = __builtin_amdgcn_mfma_f32_16x16x32_bf16(wf0, av, a0, 0, 0, 0);
            a1 = __builtin_amdgcn_mfma_f32_16x16x32_bf16(wf1, av, a1, 0, 0, 0);
        }
        aP0 = a0; aP1 = a1; tp = t;

        asm volatile("s_waitcnt vmcnt(0)" ::: "memory");
        __syncthreads();
        cur ^= 1; t = tn;
    }
    // epilogue: last tile's store
    {
        uint2 o;
        o.x = pk(silu(aP0[0] + bb0.x), silu(aP0[1] + bb0.y));
        o.y = pk(silu(aP0[2] + bb0.z), silu(aP0[3] + bb0.w));
        *(uint2*)&H1img[(size_t)tp * 4096 + (q * 4 + (qd >> 1)) * 128 + fl * 8 + (qd & 1) * 4] = o;
        o.x = pk(silu(aP1[0] + bb1.x), silu(aP1[1] + bb1.y));
        o.y = pk(silu(aP1[2] + bb1.z), silu(aP1[3] + bb1.w));
        *(uint2*)&H1img[(size_t)tp * 4096 + (q * 4 + 2 + (qd >> 1)) * 128 + fl * 8 + (qd & 1) * 4] = o;
    }
}

// ---------------------------------------------------------------------------
// Layer 2+3+pool: out[mol] += SCALE*(silu(H1@W2+b2).W3 + b3). Same R15
// cooperative-tile structure on H1img. Each wave holds a 32-col PARTIAL
// W3-dot per atom; partials go straight to the LDS bucket (additive), so
// no cross-wave reduction pass. b3 added by wave q==0 only.
// ---------------------------------------------------------------------------
__global__ __launch_bounds__(512)
void gemm2(const unsigned short* __restrict__ H1img, const unsigned short* __restrict__ Wimg,
           const float* __restrict__ b2, const float* __restrict__ W3,
           const float* __restrict__ b3, const int* __restrict__ batch,
           float* __restrict__ out) {
    __shared__ unsigned short Wlds[65536];     // 128 KB
    __shared__ unsigned short Hbuf[2][4096];   // 16 KB
    __shared__ float bucket[NMOL];             // 4 KB

    const int tid = threadIdx.x;
    const int w = tid >> 6, lane = tid & 63;
    const int fl = lane & 15, qd = lane >> 4;
    const int q = w;

#pragma unroll
    for (int i = 0; i < 16; ++i)
        async16(&Wlds[(w * 16 + i) * 512], Wimg + (w * 16 + i) * 512 + lane * 8);
    bucket[tid] = 0.0f;
    bucket[tid + 512] = 0.0f;

    const float bb0 = b2[q * 32 + fl];
    const float bb1 = b2[q * 32 + 16 + fl];
    const float w30 = W3[q * 32 + fl];
    const float w31 = W3[q * 32 + 16 + fl];
    const float b3v = (q == 0) ? b3[0] : 0.0f;   // add b3 once per atom

    int t = blockIdx.x;
    async16(&Hbuf[0][w * 512], H1img + (size_t)t * 4096 + w * 512 + lane * 8);
    asm volatile("s_waitcnt vmcnt(0)" ::: "memory");
    __syncthreads();

    int cur = 0;
    while (t < NT) {
        const int tn = t + 256;
        if (tn < NT)
            async16(&Hbuf[cur ^ 1][w * 512], H1img + (size_t)tn * 4096 + w * 512 + lane * 8);

        float4_t a0 = {}, a1 = {};
#pragma unroll
        for (int s = 0; s < 8; ++s) {
            short8 hv = *(const short8*)&Hbuf[cur][(qd + s * 4) * 128 + fl * 8];
            short8 wf0 = wfrag(Wlds, q * 32 + fl, s * 4 + qd);
            short8 wf1 = wfrag(Wlds, q * 32 + 16 + fl, s * 4 + qd);
            a0 = __builtin_amdgcn_mfma_f32_16x16x32_bf16(hv, wf0, a0, 0, 0, 0);
            a1 = __builtin_amdgcn_mfma_f32_16x16x32_bf16(hv, wf1, a1, 0, 0, 0);
        }

        // a0/a1[r]: atom = t*16 + qd*4 + r, cols q*32+fl / q*32+16+fl
        float rs[4];
#pragma unroll
        for (int r = 0; r < 4; ++r)
            rs[r] = silu(a0[r] + bb0) * w30 + silu(a1[r] + bb1) * w31;
#pragma unroll
        for (int r = 0; r < 4; ++r) {
            float v = rs[r];
            v += __shfl_xor(v, 1);
            v += __shfl_xor(v, 2);
            v += __shfl_xor(v, 4);
            v += __shfl_xor(v, 8);
            rs[r] = v;
        }
        if (fl == 0) {
            const int atom0 = t * 16 + qd * 4;    // always < N_ATOMS (NT exact)
            int4 mb = *(const int4*)&batch[atom0];
            float v0 = rs[0] + b3v, v1 = rs[1] + b3v,
                  v2 = rs[2] + b3v, v3 = rs[3] + b3v;
            if (mb.x == mb.w) {
                atomicAdd(&bucket[mb.x], (v0 + v1) + (v2 + v3));
            } else {
                atomicAdd(&bucket[mb.x], v0);
                atomicAdd(&bucket[mb.y], v1);
                atomicAdd(&bucket[mb.z], v2);
                atomicAdd(&bucket[mb.w], v3);
            }
        }

        asm volatile("s_waitcnt vmcnt(0)" ::: "memory");
        __syncthreads();
        cur ^= 1; t = tn;
    }
    __syncthreads();
#pragma unroll
    for (int i = 0; i < 2; ++i) {
        int m = tid + i * 512;
        float v = bucket[m];
        if (v != 0.0f) atomicAdd(&out[m], v * SCALE_C);
    }
}

// ---------------------------------------------------------------------------
extern "C" void kernel_launch(void* const* d_in, const int* in_sizes, int n_in,
                              void* d_out, int out_size, void* d_ws, size_t ws_size,
                              hipStream_t stream) {
    const float* A     = (const float*)d_in[0];
    const int*   batch = (const int*)d_in[1];
    const float* W1    = (const float*)d_in[2];
    const float* b1    = (const float*)d_in[3];
    const float* W2    = (const float*)d_in[4];
    const float* b2    = (const float*)d_in[5];
    const float* W3    = (const float*)d_in[6];
    const float* b3    = (const float*)d_in[7];
    float* out = (float*)d_out;

    unsigned short* H1img = (unsigned short*)d_ws;          // NT*4096 shorts
    unsigned short* W1i   = H1img + (size_t)NT * 4096;      // 65536 shorts
    unsigned short* W2i   = W1i + 65536;                    // 65536 shorts
    unsigned short* Aimg  = W2i + 65536;                    // NT*4096 shorts

    prep<<<dim3(NT + 512), 256, 0, stream>>>(W1, W2, A, W1i, W2i, Aimg, out);
    gemm1<<<dim3(256), 512, 0, stream>>>(Aimg, W1i, b1, H1img);
    gemm2<<<dim3(256), 512, 0, stream>>>(H1img, W2i, b2, W3, b3, batch, out);
}